// Round 1
// baseline (1345.309 us; speedup 1.0000x reference)
//
#include <hip/hip_runtime.h>
#include <math.h>

// NeuralGeodesicFlows: z' = [v, -0.5*g^{-1} q],  g = A A^T + I, RK4 x nsteps.
// Wave-per-point, W2 in LDS as bf16 (row stride 258 ushorts = 129 dwords, odd
// -> conflict-free for both lane-parallel-column (A stage) and
// lane-parallel-row (r stage) access). All scratch is wave-private ->
// no __syncthreads in main loop, __threadfence_block() orders LDS stages.

#define MDIM 16
#define HID 64
#define MM 256
#define W2PAD 258   // ushorts per W2 row (odd dword stride)
#define W1PAD 65    // floats per W1 row (odd)
#define GW 18       // augmented G row stride: 16 cols + q col + pad

__device__ __forceinline__ void fenceLds() { __threadfence_block(); }

__device__ __forceinline__ float bfLo(unsigned int u) { return __uint_as_float(u << 16); }
__device__ __forceinline__ float bfHi(unsigned int u) { return __uint_as_float(u & 0xffff0000u); }

__device__ __forceinline__ unsigned short f2bf(float f) {
    unsigned int u = __float_as_uint(f);
    u += 0x7fffu + ((u >> 16) & 1u);   // round to nearest even
    return (unsigned short)(u >> 16);
}

__device__ __forceinline__ void evalF(int l,
        const unsigned short* sW2, const float* sW1, const float* sb1, const float* sb2,
        const float* zI, float* hw, float* Aw, float* ww, float* tw, float* Gw, float* kv)
{
    // ---- load x, v (broadcast b128 reads) ----
    float x[MDIM], v[MDIM];
    #pragma unroll
    for (int m2 = 0; m2 < 4; ++m2) {
        float4 xx = *(const float4*)&zI[4 * m2];
        float4 vv = *(const float4*)&zI[MDIM + 4 * m2];
        x[4*m2+0] = xx.x; x[4*m2+1] = xx.y; x[4*m2+2] = xx.z; x[4*m2+3] = xx.w;
        v[4*m2+0] = vv.x; v[4*m2+1] = vv.y; v[4*m2+2] = vv.z; v[4*m2+3] = vv.w;
    }
    // ---- h stage: lane l computes h_l ----
    float hval, dval;
    {
        float acc = sb1[l];
        #pragma unroll
        for (int i = 0; i < MDIM; ++i) acc += x[i] * sW1[i * W1PAD + l];
        hval = tanhf(acc);
        dval = 1.0f - hval * hval;
        hw[l] = hval;
    }
    fenceLds();
    // ---- A stage: lane l computes A_flat[4l..4l+3] ----
    {
        float4 b2v = *(const float4*)&sb2[4 * l];
        float a0 = b2v.x, a1 = b2v.y, a2 = b2v.z, a3 = b2v.w;
        #pragma unroll 4
        for (int m = 0; m < 16; ++m) {
            float4 h4 = *(const float4*)&hw[4 * m];
            float hh[4] = {h4.x, h4.y, h4.z, h4.w};
            #pragma unroll
            for (int u = 0; u < 4; ++u) {
                int n = 4 * m + u;
                unsigned int p0 = *(const unsigned int*)&sW2[n * W2PAD + 4 * l];
                unsigned int p1 = *(const unsigned int*)&sW2[n * W2PAD + 4 * l + 2];
                float hn = hh[u];
                a0 += hn * bfLo(p0);
                a1 += hn * bfHi(p0);
                a2 += hn * bfLo(p1);
                a3 += hn * bfHi(p1);
            }
        }
        int aa = l >> 2;          // (4l)>>4
        int c0 = (4 * l) & 15;
        Aw[aa * 17 + c0 + 0] = a0;
        Aw[aa * 17 + c0 + 1] = a1;
        Aw[aa * 17 + c0 + 2] = a2;
        Aw[aa * 17 + c0 + 3] = a3;
    }
    fenceLds();
    // ---- w stage: w_c = sum_a v_a A[a][c]  (lanes < 16) ----
    if (l < MDIM) {
        float wc = 0.0f;
        #pragma unroll
        for (int a = 0; a < MDIM; ++a) wc += v[a] * Aw[a * 17 + l];
        ww[l] = wc;
    }
    fenceLds();
    float wreg[MDIM];
    #pragma unroll
    for (int m2 = 0; m2 < 4; ++m2) {
        float4 w4 = *(const float4*)&ww[4 * m2];
        wreg[4*m2+0] = w4.x; wreg[4*m2+1] = w4.y; wreg[4*m2+2] = w4.z; wreg[4*m2+3] = w4.w;
    }
    // ---- g stage: G[aa][bb] = delta + sum_c A[aa][c] A[bb][c] ----
    {
        int bb = l & 15;
        float Ab[MDIM];
        #pragma unroll
        for (int c = 0; c < MDIM; ++c) Ab[c] = Aw[bb * 17 + c];
        #pragma unroll
        for (int j4 = 0; j4 < 4; ++j4) {
            int aa = (l >> 4) + 4 * j4;
            float gacc = (aa == bb) ? 1.0f : 0.0f;
            #pragma unroll
            for (int c = 0; c < MDIM; ++c) gacc += Aw[aa * 17 + c] * Ab[c];
            Gw[aa * GW + bb] = gacc;
        }
    }
    // ---- r stage: lane l = n: r_n = sum_{a,c} v_a w_c W2[n][16a+c]; t_n = d_n r_n ----
    {
        float racc = 0.0f;
        #pragma unroll 4
        for (int a = 0; a < MDIM; ++a) {
            float ca = 0.0f;
            #pragma unroll
            for (int k4 = 0; k4 < 4; ++k4) {
                unsigned int p0 = *(const unsigned int*)&sW2[l * W2PAD + 16 * a + 4 * k4];
                unsigned int p1 = *(const unsigned int*)&sW2[l * W2PAD + 16 * a + 4 * k4 + 2];
                ca += bfLo(p0) * wreg[4 * k4 + 0];
                ca += bfHi(p0) * wreg[4 * k4 + 1];
                ca += bfLo(p1) * wreg[4 * k4 + 2];
                ca += bfHi(p1) * wreg[4 * k4 + 3];
            }
            racc += v[a] * ca;
        }
        tw[l] = dval * racc;
    }
    fenceLds();
    // ---- q stage: q_i = 2 sum_n t_n W1[i][n] -> augmented col of G ----
    if (l < MDIM) {
        float qi = 0.0f;
        #pragma unroll 4
        for (int m = 0; m < 16; ++m) {
            float4 t4 = *(const float4*)&tw[4 * m];
            float tt[4] = {t4.x, t4.y, t4.z, t4.w};
            #pragma unroll
            for (int u = 0; u < 4; ++u)
                qi += tt[u] * sW1[l * W1PAD + 4 * m + u];
        }
        Gw[l * GW + MDIM] = 2.0f * qi;
    }
    fenceLds();
    // ---- solve G y = q: unnormalized Gauss-Jordan (SPD, pivots >= 1) ----
    #pragma unroll 1
    for (int k = 0; k < MDIM; ++k) {
        float pinv = __builtin_amdgcn_rcpf(Gw[k * GW + k]);
        int j = l & 15;
        float gkj = Gw[k * GW + j];
        float gkq = Gw[k * GW + MDIM];
        #pragma unroll
        for (int mr = 0; mr < 4; ++mr) {
            int i = (l >> 4) + 4 * mr;
            if (i != k) {
                float fik = Gw[i * GW + k] * pinv;
                Gw[i * GW + j] -= fik * gkj;
                if (j == 0) Gw[i * GW + MDIM] -= fik * gkq;
            }
        }
        fenceLds();
    }
    if (l < MDIM) {
        float y = Gw[l * GW + MDIM] * __builtin_amdgcn_rcpf(Gw[l * GW + l]);
        kv[MDIM + l] = -0.5f * y;   // dv
        kv[l] = zI[MDIM + l];       // dx = v
    }
    fenceLds();
}

__global__ __launch_bounds__(256, 3)
void geo_kernel(const float* __restrict__ zin_g,
                const float* __restrict__ t_g,
                const float* __restrict__ W1_g,
                const float* __restrict__ b1_g,
                const float* __restrict__ W2_g,
                const float* __restrict__ b2_g,
                const int* __restrict__ ns_g,
                float* __restrict__ out_g,
                int B)
{
    __shared__ __align__(16) unsigned short sW2[HID * W2PAD];
    __shared__ __align__(16) float sW1[MDIM * W1PAD];
    __shared__ __align__(16) float sb1[HID];
    __shared__ __align__(16) float sb2[MM];
    __shared__ __align__(16) float sh[4][HID];
    __shared__ __align__(16) float sA[4][MDIM * 17];
    __shared__ __align__(16) float sG[4][MDIM * GW];
    __shared__ __align__(16) float st_[4][HID];
    __shared__ __align__(16) float sw_[4][MDIM];
    __shared__ __align__(16) float sz[4][2 * MDIM];
    __shared__ __align__(16) float szi[4][2 * MDIM];
    __shared__ __align__(16) float sac[4][2 * MDIM];
    __shared__ __align__(16) float sk[4][2 * MDIM];

    const int tid = threadIdx.x;
    for (int idx = tid; idx < HID * MM; idx += 256) {
        int n = idx >> 8, e = idx & 255;
        sW2[n * W2PAD + e] = f2bf(W2_g[idx]);
    }
    for (int idx = tid; idx < MDIM * HID; idx += 256)
        sW1[(idx >> 6) * W1PAD + (idx & 63)] = W1_g[idx];
    if (tid < HID) sb1[tid] = b1_g[tid];
    if (tid < MM) sb2[tid] = b2_g[tid];
    __syncthreads();

    const float tval = t_g[0];
    const int nsteps = ns_g[0];
    const float dt = tval / (float)nsteps;

    const int w = tid >> 6;
    const int l = tid & 63;

    float* zC = sz[w];
    float* zI = szi[w];
    float* ac = sac[w];
    float* kv = sk[w];
    float* Aw = sA[w];
    float* Gw = sG[w];
    float* hw = sh[w];
    float* tw = st_[w];
    float* ww = sw_[w];

    const int gwave = blockIdx.x * 4 + w;
    const int nwaves = gridDim.x * 4;

    for (int p = gwave; p < B; p += nwaves) {
        if (l < 2 * MDIM) zC[l] = zin_g[p * 2 * MDIM + l];
        fenceLds();
        for (int step = 0; step < nsteps; ++step) {
            if (l < 2 * MDIM) zI[l] = zC[l];
            fenceLds();
            #pragma unroll 1
            for (int s = 0; s < 4; ++s) {
                evalF(l, sW2, sW1, sb1, sb2, zI, hw, Aw, ww, tw, Gw, kv);
                if (l < 2 * MDIM) {
                    float kk = kv[l];
                    float wgt = (s == 0 || s == 3) ? 1.0f : 2.0f;
                    float a = (s == 0) ? kk : ac[l] + wgt * kk;
                    ac[l] = a;
                    if (s == 0 || s == 1)      zI[l] = zC[l] + (0.5f * dt) * kk;
                    else if (s == 2)           zI[l] = zC[l] + dt * kk;
                    else                       zC[l] = zC[l] + (dt / 6.0f) * a;
                }
                fenceLds();
            }
        }
        if (l < 2 * MDIM) out_g[p * 2 * MDIM + l] = zC[l];
    }
}

extern "C" void kernel_launch(void* const* d_in, const int* in_sizes, int n_in,
                              void* d_out, int out_size, void* d_ws, size_t ws_size,
                              hipStream_t stream) {
    (void)n_in; (void)d_ws; (void)ws_size; (void)out_size;
    const float* z  = (const float*)d_in[0];
    const float* t  = (const float*)d_in[1];
    const float* W1 = (const float*)d_in[2];
    const float* b1 = (const float*)d_in[3];
    const float* W2 = (const float*)d_in[4];
    const float* b2 = (const float*)d_in[5];
    const int*   ns = (const int*)d_in[6];
    float* out = (float*)d_out;
    const int B = in_sizes[0] / (2 * MDIM);
    int grid = 768;                       // 3 blocks/CU x 256 CUs, single residency round
    if (grid * 4 > B) grid = (B + 3) / 4;
    hipLaunchKernelGGL(geo_kernel, dim3(grid), dim3(256), 0, stream,
                       z, t, W1, b1, W2, b2, ns, out, B);
}

// Round 2
// 1162.745 us; speedup vs baseline: 1.1570x; 1.1570x over previous
//
#include <hip/hip_runtime.h>
#include <math.h>

// NeuralGeodesicFlows: z' = [v, -0.5*g^{-1} q],  g = A A^T + I, RK4 x nsteps.
// Wave-per-point; 8 waves/block share one bf16 W2 LDS copy (row stride 264
// ushorts = 16B-aligned rows, granule stride odd -> conflict-free b128 row
// reads in r-stage). A-stage: lane l owns A elements {2l,2l+1,128+2l,129+2l}
// -> stride-1 dword reads (conflict-free), ds_read2-fusable.
// All per-wave scratch is wave-private -> no __syncthreads in main loop;
// __threadfence_block() (lgkmcnt drain) orders stages within the wave.

#define MDIM 16
#define HID 64
#define MM 256
#define W2PAD 264   // ushorts per W2 row: 132 dwords, 16B-aligned, 33-granule odd
#define W1PAD 65    // floats per W1 row (odd)
#define AW 18       // A row stride (even -> aligned float2 writes)
#define GW 18       // augmented G row stride: 16 cols + q col + pad
#define WAVES 8     // waves per block

__device__ __forceinline__ void fenceLds() { __threadfence_block(); }

__device__ __forceinline__ float bfLo(unsigned int u) { return __uint_as_float(u << 16); }
__device__ __forceinline__ float bfHi(unsigned int u) { return __uint_as_float(u & 0xffff0000u); }

__device__ __forceinline__ unsigned short f2bf(float f) {
    unsigned int u = __float_as_uint(f);
    u += 0x7fffu + ((u >> 16) & 1u);   // round to nearest even
    return (unsigned short)(u >> 16);
}

__device__ __forceinline__ float fastTanh(float x) {
    // tanh(x) = 1 - 2/(1 + 2^(x*2*log2e)); saturates correctly at +-inf
#if __has_builtin(__builtin_amdgcn_exp2f)
    float e = __builtin_amdgcn_exp2f(x * 2.885390081777927f);
#else
    float e = exp2f(x * 2.885390081777927f);
#endif
    return 1.0f - 2.0f * __builtin_amdgcn_rcpf(1.0f + e);
}

__device__ __forceinline__ void evalF(int l,
        const unsigned short* sW2, const float* sW1, const float* sb1, const float* sb2,
        const float* zI, float* ht, float* Aw, float* ww, float* Gw, float* kv)
{
    // ---- load x, v (broadcast b128 reads) ----
    float x[MDIM], v[MDIM];
    #pragma unroll
    for (int m2 = 0; m2 < 4; ++m2) {
        float4 xx = *(const float4*)&zI[4 * m2];
        float4 vv = *(const float4*)&zI[MDIM + 4 * m2];
        x[4*m2+0] = xx.x; x[4*m2+1] = xx.y; x[4*m2+2] = xx.z; x[4*m2+3] = xx.w;
        v[4*m2+0] = vv.x; v[4*m2+1] = vv.y; v[4*m2+2] = vv.z; v[4*m2+3] = vv.w;
    }
    // ---- h stage: lane l computes h_l ----
    float dval;
    {
        float acc = sb1[l];
        #pragma unroll
        for (int i = 0; i < MDIM; ++i) acc += x[i] * sW1[i * W1PAD + l];
        float hval = fastTanh(acc);
        dval = 1.0f - hval * hval;
        ht[l] = hval;
    }
    fenceLds();
    // ---- A stage: lane l computes A_flat[{2l,2l+1,128+2l,129+2l}] ----
    // reads dwords n*132 + l and n*132 + 64 + l : stride-1 across lanes.
    {
        float2 bA = *(const float2*)&sb2[2 * l];
        float2 bB = *(const float2*)&sb2[128 + 2 * l];
        float a0 = bA.x, a1 = bA.y, a2 = bB.x, a3 = bB.y;
        #pragma unroll 4
        for (int m = 0; m < 16; ++m) {
            float4 h4 = *(const float4*)&ht[4 * m];
            float hh[4] = {h4.x, h4.y, h4.z, h4.w};
            #pragma unroll
            for (int u = 0; u < 4; ++u) {
                int n = 4 * m + u;
                unsigned int p0 = *(const unsigned int*)&sW2[n * W2PAD + 2 * l];
                unsigned int p1 = *(const unsigned int*)&sW2[n * W2PAD + 128 + 2 * l];
                float hn = hh[u];
                a0 += hn * bfLo(p0);
                a1 += hn * bfHi(p0);
                a2 += hn * bfLo(p1);
                a3 += hn * bfHi(p1);
            }
        }
        int aa = l >> 3;          // row of e=2l
        int cc = (2 * l) & 15;
        *(float2*)&Aw[aa * AW + cc] = make_float2(a0, a1);
        *(float2*)&Aw[(aa + 8) * AW + cc] = make_float2(a2, a3);
    }
    fenceLds();
    // ---- w stage: w_c = sum_a v_a A[a][c]  (lanes < 16) ----
    if (l < MDIM) {
        float wc = 0.0f;
        #pragma unroll
        for (int a = 0; a < MDIM; ++a) wc += v[a] * Aw[a * AW + l];
        ww[l] = wc;
    }
    fenceLds();
    float wreg[MDIM];
    #pragma unroll
    for (int m2 = 0; m2 < 4; ++m2) {
        float4 w4 = *(const float4*)&ww[4 * m2];
        wreg[4*m2+0] = w4.x; wreg[4*m2+1] = w4.y; wreg[4*m2+2] = w4.z; wreg[4*m2+3] = w4.w;
    }
    // ---- g stage: G[aa][bb] = delta + sum_c A[aa][c] A[bb][c] ----
    {
        int bb = l & 15;
        float Ab[MDIM];
        #pragma unroll
        for (int c = 0; c < MDIM; ++c) Ab[c] = Aw[bb * AW + c];
        #pragma unroll
        for (int j4 = 0; j4 < 4; ++j4) {
            int aa = (l >> 4) + 4 * j4;
            float gacc = (aa == bb) ? 1.0f : 0.0f;
            #pragma unroll
            for (int c = 0; c < MDIM; ++c) gacc += Aw[aa * AW + c] * Ab[c];
            Gw[aa * GW + bb] = gacc;
        }
    }
    // ---- r stage: lane l = n: r_n = sum_{a,c} v_a w_c W2[n][16a+c]; t_n = d_n r_n ----
    // overwrites ht (h fully consumed in A stage; fences since then)
    {
        float racc = 0.0f;
        #pragma unroll 4
        for (int a = 0; a < MDIM; ++a) {
            uint4 p = *(const uint4*)&sW2[l * W2PAD + 16 * a];
            uint4 q = *(const uint4*)&sW2[l * W2PAD + 16 * a + 8];
            float ca = bfLo(p.x) * wreg[0] + bfHi(p.x) * wreg[1]
                     + bfLo(p.y) * wreg[2] + bfHi(p.y) * wreg[3]
                     + bfLo(p.z) * wreg[4] + bfHi(p.z) * wreg[5]
                     + bfLo(p.w) * wreg[6] + bfHi(p.w) * wreg[7]
                     + bfLo(q.x) * wreg[8] + bfHi(q.x) * wreg[9]
                     + bfLo(q.y) * wreg[10] + bfHi(q.y) * wreg[11]
                     + bfLo(q.z) * wreg[12] + bfHi(q.z) * wreg[13]
                     + bfLo(q.w) * wreg[14] + bfHi(q.w) * wreg[15];
            racc += v[a] * ca;
        }
        ht[l] = dval * racc;
    }
    fenceLds();
    // ---- q stage: q_i = 2 sum_n t_n W1[i][n] -> augmented col of G ----
    if (l < MDIM) {
        float qi = 0.0f;
        #pragma unroll 4
        for (int m = 0; m < 16; ++m) {
            float4 t4 = *(const float4*)&ht[4 * m];
            float tt[4] = {t4.x, t4.y, t4.z, t4.w};
            #pragma unroll
            for (int u = 0; u < 4; ++u)
                qi += tt[u] * sW1[l * W1PAD + 4 * m + u];
        }
        Gw[l * GW + MDIM] = 2.0f * qi;
    }
    fenceLds();
    // ---- solve G y = q: unnormalized Gauss-Jordan (SPD, pivots >= 1) ----
    #pragma unroll 1
    for (int k = 0; k < MDIM; ++k) {
        float pinv = __builtin_amdgcn_rcpf(Gw[k * GW + k]);
        int j = l & 15;
        float gkj = Gw[k * GW + j];
        float gkq = Gw[k * GW + MDIM];
        #pragma unroll
        for (int mr = 0; mr < 4; ++mr) {
            int i = (l >> 4) + 4 * mr;
            if (i != k) {
                float fik = Gw[i * GW + k] * pinv;
                Gw[i * GW + j] -= fik * gkj;
                if (j == 0) Gw[i * GW + MDIM] -= fik * gkq;
            }
        }
        fenceLds();
    }
    if (l < MDIM) {
        float y = Gw[l * GW + MDIM] * __builtin_amdgcn_rcpf(Gw[l * GW + l]);
        kv[MDIM + l] = -0.5f * y;   // dv
        kv[l] = zI[MDIM + l];       // dx = v
    }
    fenceLds();
}

__global__ __launch_bounds__(512, 4)
void geo_kernel(const float* __restrict__ zin_g,
                const float* __restrict__ t_g,
                const float* __restrict__ W1_g,
                const float* __restrict__ b1_g,
                const float* __restrict__ W2_g,
                const float* __restrict__ b2_g,
                const int* __restrict__ ns_g,
                float* __restrict__ out_g,
                int B)
{
    __shared__ __align__(16) unsigned short sW2[HID * W2PAD];   // 33792 B
    __shared__ __align__(16) float sW1[MDIM * W1PAD];           //  4160 B
    __shared__ __align__(16) float sb1[HID];
    __shared__ __align__(16) float sb2[MM];
    __shared__ __align__(16) float sht[WAVES][HID];             // h, then t
    __shared__ __align__(16) float sA[WAVES][MDIM * AW];
    __shared__ __align__(16) float sG[WAVES][MDIM * GW];
    __shared__ __align__(16) float sw_[WAVES][MDIM];
    __shared__ __align__(16) float sz[WAVES][2 * MDIM];
    __shared__ __align__(16) float szi[WAVES][2 * MDIM];
    __shared__ __align__(16) float sac[WAVES][2 * MDIM];
    __shared__ __align__(16) float sk[WAVES][2 * MDIM];

    const int tid = threadIdx.x;
    for (int idx = tid; idx < HID * MM; idx += 512) {
        int n = idx >> 8, e = idx & 255;
        sW2[n * W2PAD + e] = f2bf(W2_g[idx]);
    }
    for (int idx = tid; idx < MDIM * HID; idx += 512)
        sW1[(idx >> 6) * W1PAD + (idx & 63)] = W1_g[idx];
    if (tid < HID) sb1[tid] = b1_g[tid];
    if (tid < MM) sb2[tid] = b2_g[tid];
    __syncthreads();

    const float tval = t_g[0];
    const int nsteps = ns_g[0];
    const float dt = tval / (float)nsteps;

    const int w = tid >> 6;
    const int l = tid & 63;

    float* zC = sz[w];
    float* zI = szi[w];
    float* ac = sac[w];
    float* kv = sk[w];
    float* Aw = sA[w];
    float* Gw = sG[w];
    float* ht = sht[w];
    float* ww = sw_[w];

    const int gwave = blockIdx.x * WAVES + w;
    const int nwaves = gridDim.x * WAVES;

    for (int p = gwave; p < B; p += nwaves) {
        if (l < 2 * MDIM) zC[l] = zin_g[p * 2 * MDIM + l];
        fenceLds();
        for (int step = 0; step < nsteps; ++step) {
            if (l < 2 * MDIM) zI[l] = zC[l];
            fenceLds();
            #pragma unroll 1
            for (int s = 0; s < 4; ++s) {
                evalF(l, sW2, sW1, sb1, sb2, zI, ht, Aw, ww, Gw, kv);
                if (l < 2 * MDIM) {
                    float kk = kv[l];
                    float wgt = (s == 0 || s == 3) ? 1.0f : 2.0f;
                    float a = (s == 0) ? kk : ac[l] + wgt * kk;
                    ac[l] = a;
                    if (s == 0 || s == 1)      zI[l] = zC[l] + (0.5f * dt) * kk;
                    else if (s == 2)           zI[l] = zC[l] + dt * kk;
                    else                       zC[l] = zC[l] + (dt / 6.0f) * a;
                }
                fenceLds();
            }
        }
        if (l < 2 * MDIM) out_g[p * 2 * MDIM + l] = zC[l];
    }
}

extern "C" void kernel_launch(void* const* d_in, const int* in_sizes, int n_in,
                              void* d_out, int out_size, void* d_ws, size_t ws_size,
                              hipStream_t stream) {
    (void)n_in; (void)d_ws; (void)ws_size; (void)out_size;
    const float* z  = (const float*)d_in[0];
    const float* t  = (const float*)d_in[1];
    const float* W1 = (const float*)d_in[2];
    const float* b1 = (const float*)d_in[3];
    const float* W2 = (const float*)d_in[4];
    const float* b2 = (const float*)d_in[5];
    const int*   ns = (const int*)d_in[6];
    float* out = (float*)d_out;
    const int B = in_sizes[0] / (2 * MDIM);
    int grid = (B + 4 * WAVES - 1) / (4 * WAVES);   // 4 points per wave
    if (grid > 512) grid = 512;                     // 2 blocks/CU x 256 CUs
    hipLaunchKernelGGL(geo_kernel, dim3(grid), dim3(512), 0, stream,
                       z, t, W1, b1, W2, b2, ns, out, B);
}

// Round 3
// 330.511 us; speedup vs baseline: 4.0704x; 3.5180x over previous
//
#include <hip/hip_runtime.h>
#include <math.h>

// v3: 16 points per wave, f16 MFMA for all batched contractions, register GJ solve.
// dv = G^{-1} qfold,  G = A A^T + I,  qfold = -sum_n W1[i][n] d_n r_n  (d,0.5,2,sign folded)
// One wave per block (64 thr), 1024 blocks, 4 blocks/CU, ~1 wave/SIMD by design.

typedef _Float16 f16;
typedef _Float16 f16x4 __attribute__((ext_vector_type(4)));
typedef _Float16 f16x8 __attribute__((ext_vector_type(8)));
typedef float f32x4 __attribute__((ext_vector_type(4)));
typedef float f32x16 __attribute__((ext_vector_type(16)));

#define SA_P 392   // f16 stride: sA/sG point stride (row stride 24)
#define SZ_P 36    // f32 stride: z buffers
#define SH_P 72    // f16 stride: sHT/sD
#define SW_P 20    // f32 stride: sWw / sKV

__device__ __forceinline__ void F() { __threadfence_block(); }

__device__ __forceinline__ float fastTanh(float x) {
    float e = exp2f(x * 2.885390081777927f);
    return 1.0f - 2.0f * __builtin_amdgcn_rcpf(1.0f + e);
}

__global__ __launch_bounds__(64, 1)
void geo_kernel(const float* __restrict__ zin, const float* __restrict__ tg,
                const float* __restrict__ W1g, const float* __restrict__ b1g,
                const float* __restrict__ W2g, const float* __restrict__ b2g,
                const int* __restrict__ nsg, float* __restrict__ outg, int B)
{
    __shared__ __align__(16) f16   sA [16*SA_P];  // [p][a][c] f16
    __shared__ __align__(16) f16   sG [16*SA_P];  // [p][row][0..16] f16 (aug at 16)
    __shared__ __align__(16) float sZC[16*SZ_P];
    __shared__ __align__(16) float sZI[16*SZ_P];
    __shared__ __align__(16) float sAC[16*SZ_P];
    __shared__ __align__(16) float sKV[16*SW_P];  // dv per point
    __shared__ __align__(16) f16   sHT[16*SH_P];  // h, later t
    __shared__ __align__(16) f16   sD [16*SH_P];  // -(1-h^2)
    __shared__ __align__(16) float sWw[16*SW_P];  // w per point

    const int l = threadIdx.x;
    const int i16 = l & 15, q4 = l >> 4, h2 = l >> 5;
    const int sc = q4 & 1;            // == (l&31)>>4
    const int lam = l & 3, pl = l >> 2, c4 = l & 3;

    // ---------------- hoisted weights (one-time) ----------------
    f16x8 w2a[16][2];                 // A-stage B-frag: B[k=n][e]; n=8q4+j+32ch, e=i16+16t
    #pragma unroll
    for (int t = 0; t < 16; ++t)
        #pragma unroll
        for (int ch = 0; ch < 2; ++ch)
            #pragma unroll
            for (int j = 0; j < 8; ++j)
                w2a[t][ch][j] = (f16)W2g[(8*q4 + j + 32*ch)*256 + i16 + 16*t];

    f16x8 w2r[4][8];                  // r-stage B-frag: B[k=e][n]; n=i16+16t4, e=8q4+j+32ch
    #pragma unroll
    for (int t = 0; t < 4; ++t)
        #pragma unroll
        for (int ch = 0; ch < 8; ++ch)
            #pragma unroll
            for (int j = 0; j < 8; ++j)
                w2r[t][ch][j] = (f16)W2g[(i16 + 16*t)*256 + 8*q4 + j + 32*ch];

    f16x8 w1h[4];                     // H-stage B-frag: B[k=xdim][n]; K zero-padded 16->32
    #pragma unroll
    for (int t = 0; t < 4; ++t)
        #pragma unroll
        for (int j = 0; j < 8; ++j) {
            int k = 8*q4 + j;
            w1h[t][j] = (k < 16) ? (f16)W1g[k*64 + i16 + 16*t] : (f16)0.0f;
        }

    f16x8 w1q[2];                     // q-stage B-frag: B[k=n][i]; i=i16
    #pragma unroll
    for (int ch = 0; ch < 2; ++ch)
        #pragma unroll
        for (int j = 0; j < 8; ++j)
            w1q[ch][j] = (f16)W1g[i16*64 + 8*q4 + j + 32*ch];

    float b2v[16], b1v[4];
    #pragma unroll
    for (int t = 0; t < 16; ++t) b2v[t] = b2g[i16 + 16*t];
    #pragma unroll
    for (int t = 0; t < 4; ++t) b1v[t] = b1g[i16 + 16*t];

    f32x16 eyeC;                      // identity in 32x32 C-layout
    #pragma unroll
    for (int r = 0; r < 16; ++r) {
        int row = (r & 3) + 8*(r >> 2) + 4*h2;
        eyeC[r] = (row == (l & 31)) ? 1.0f : 0.0f;
    }

    // ---------------- stage z ----------------
    const int pb = blockIdx.x * 16;
    const int pgi = (pb + pl < B) ? (pb + pl) : (B - 1);
    {
        f32x4 za = *(const f32x4*)&zin[pgi*32 + 8*c4];
        f32x4 zb = *(const f32x4*)&zin[pgi*32 + 8*c4 + 4];
        *(f32x4*)&sZC[pl*SZ_P + 8*c4]     = za;
        *(f32x4*)&sZC[pl*SZ_P + 8*c4 + 4] = zb;
    }
    F();

    const float tv = tg[0];
    const int nst = nsg[0];
    const float dt = tv / (float)nst;

    #pragma unroll 1
    for (int st = 0; st < nst; ++st) {
        // zI = zC
        {
            f32x4 a = *(const f32x4*)&sZC[pl*SZ_P + 8*c4];
            f32x4 b = *(const f32x4*)&sZC[pl*SZ_P + 8*c4 + 4];
            *(f32x4*)&sZI[pl*SZ_P + 8*c4]     = a;
            *(f32x4*)&sZI[pl*SZ_P + 8*c4 + 4] = b;
        }
        F();
        #pragma unroll 1
        for (int s = 0; s < 4; ++s) {
            // ======== H-stage: H = tanh(X@W1 + b1) ========
            {
                f16x8 xf;
                {
                    f32x4 xa = *(const f32x4*)&sZI[i16*SZ_P + 8*(q4 & 1)];
                    f32x4 xb = *(const f32x4*)&sZI[i16*SZ_P + 8*(q4 & 1) + 4];
                    #pragma unroll
                    for (int j = 0; j < 4; ++j) { xf[j] = (f16)xa[j]; xf[4+j] = (f16)xb[j]; }
                }
                #pragma unroll
                for (int t = 0; t < 4; ++t) {
                    f32x4 hc = {0.f, 0.f, 0.f, 0.f};
                    hc = __builtin_amdgcn_mfma_f32_16x16x32_f16(xf, w1h[t], hc, 0, 0, 0);
                    #pragma unroll
                    for (int reg = 0; reg < 4; ++reg) {
                        float hv = fastTanh(hc[reg] + b1v[t]);
                        int off = (4*q4 + reg)*SH_P + i16 + 16*t;
                        sHT[off] = (f16)hv;
                        sD[off]  = (f16)(hv*hv - 1.0f);   // -(1-h^2)
                    }
                }
            }
            F();
            // ======== A-stage: A = H@W2 + b2 -> sA[p][a][c] f16 ========
            {
                f16x8 hf0 = *(const f16x8*)&sHT[i16*SH_P + 8*q4];
                f16x8 hf1 = *(const f16x8*)&sHT[i16*SH_P + 8*q4 + 32];
                #pragma unroll
                for (int t = 0; t < 16; ++t) {
                    f32x4 ac = {0.f, 0.f, 0.f, 0.f};
                    ac = __builtin_amdgcn_mfma_f32_16x16x32_f16(hf0, w2a[t][0], ac, 0, 0, 0);
                    ac = __builtin_amdgcn_mfma_f32_16x16x32_f16(hf1, w2a[t][1], ac, 0, 0, 0);
                    #pragma unroll
                    for (int reg = 0; reg < 4; ++reg)
                        sA[(4*q4 + reg)*SA_P + 24*t + i16] = (f16)(ac[reg] + b2v[t]);
                }
            }
            F();
            // ======== v-load + w-stage: w_c = sum_a v_a A[a][c] (lane: p=i16, cols 4q4..+3) ========
            float vreg[16];
            {
                #pragma unroll
                for (int m = 0; m < 4; ++m) {
                    f32x4 v4 = *(const f32x4*)&sZI[i16*SZ_P + 16 + 4*m];
                    #pragma unroll
                    for (int j = 0; j < 4; ++j) vreg[4*m + j] = v4[j];
                }
                float w4[4] = {0.f, 0.f, 0.f, 0.f};
                #pragma unroll
                for (int a = 0; a < 16; ++a) {
                    f16x4 av = *(const f16x4*)&sA[i16*SA_P + 24*a + 4*q4];
                    #pragma unroll
                    for (int u = 0; u < 4; ++u) w4[u] += vreg[a] * (float)av[u];
                }
                f32x4 wv4 = {w4[0], w4[1], w4[2], w4[3]};
                *(f32x4*)&sWw[i16*SW_P + 4*q4] = wv4;
            }
            // ======== AA^T (pairs, 32x32x16) + G transport (f16) ========
            #pragma unroll
            for (int u = 0; u < 8; ++u) {
                f16x8 af = *(const f16x8*)&sA[(2*u + sc)*SA_P + 24*i16 + 8*h2];
                f32x16 g = __builtin_amdgcn_mfma_f32_32x32x16_f16(af, af, eyeC, 0, 0, 0);
                #pragma unroll
                for (int rr = 0; rr < 8; ++rr) {
                    int a_ = (rr & 3) + 8*(rr >> 2) + 4*h2;
                    sG[(2*u + sc)*SA_P + 24*a_ + i16] = (f16)g[rr + 8*sc];
                }
            }
            F();
            // ======== U = v (x) w  +  r-stage: R = U @ W2^T ========
            f32x4 racc[4];
            #pragma unroll
            for (int t = 0; t < 4; ++t) { f32x4 z = {0.f,0.f,0.f,0.f}; racc[t] = z; }
            {
                float wv[8];
                f32x4 wa = *(const f32x4*)&sWw[i16*SW_P + 8*(q4 & 1)];
                f32x4 wb = *(const f32x4*)&sWw[i16*SW_P + 8*(q4 & 1) + 4];
                #pragma unroll
                for (int j = 0; j < 4; ++j) { wv[j] = wa[j]; wv[4+j] = wb[j]; }
                #pragma unroll
                for (int ch = 0; ch < 8; ++ch) {
                    float vv = vreg[2*ch + (q4 >> 1)];
                    f16x8 uf;
                    #pragma unroll
                    for (int j = 0; j < 8; ++j) uf[j] = (f16)(vv * wv[j]);
                    #pragma unroll
                    for (int t = 0; t < 4; ++t)
                        racc[t] = __builtin_amdgcn_mfma_f32_16x16x32_f16(uf, w2r[t][ch], racc[t], 0, 0, 0);
                }
            }
            // r-epilogue: T = (-d) * R -> sHT (overwrites h)
            #pragma unroll
            for (int t = 0; t < 4; ++t)
                #pragma unroll
                for (int reg = 0; reg < 4; ++reg) {
                    int off = (4*q4 + reg)*SH_P + i16 + 16*t;
                    float dn = (float)sD[off];
                    sHT[off] = (f16)(dn * racc[t][reg]);
                }
            F();
            // ======== q-stage: aug = T @ W1^T -> sG[p][i][16] ========
            {
                f16x8 tf0 = *(const f16x8*)&sHT[i16*SH_P + 8*q4];
                f16x8 tf1 = *(const f16x8*)&sHT[i16*SH_P + 8*q4 + 32];
                f32x4 qa = {0.f, 0.f, 0.f, 0.f};
                qa = __builtin_amdgcn_mfma_f32_16x16x32_f16(tf0, w1q[0], qa, 0, 0, 0);
                qa = __builtin_amdgcn_mfma_f32_16x16x32_f16(tf1, w1q[1], qa, 0, 0, 0);
                #pragma unroll
                for (int reg = 0; reg < 4; ++reg)
                    sG[(4*q4 + reg)*SA_P + 24*i16 + 16] = (f16)qa[reg];
            }
            F();
            // ======== solve G y = aug in registers; lane = (p=pl, rows lam+4i) ========
            {
                float R[4][17];
                #pragma unroll
                for (int i = 0; i < 4; ++i) {
                    const f16* rp = &sG[pl*SA_P + 24*(lam + 4*i)];
                    f16x8 ra = *(const f16x8*)&rp[0];
                    f16x8 rb = *(const f16x8*)&rp[8];
                    #pragma unroll
                    for (int j = 0; j < 8; ++j) { R[i][j] = (float)ra[j]; R[i][8+j] = (float)rb[j]; }
                    R[i][16] = (float)rp[16];
                }
                // forward elimination
                #pragma unroll
                for (int k = 0; k < 16; ++k) {
                    const int src = (l & ~3) | (k & 3);
                    float pv[17];
                    #pragma unroll
                    for (int j = k; j < 17; ++j) pv[j] = __shfl(R[k >> 2][j], src);
                    float pinv = __builtin_amdgcn_rcpf(pv[k]);
                    #pragma unroll
                    for (int i = 0; i < 4; ++i) {
                        int gr = lam + 4*i;
                        float f = (gr > k) ? (R[i][k] * pinv) : 0.0f;
                        #pragma unroll
                        for (int j = k + 1; j < 17; ++j) R[i][j] -= f * pv[j];
                    }
                }
                // back substitution
                float ys[4];
                #pragma unroll
                for (int i = 0; i < 4; ++i) ys[i] = 0.0f;
                #pragma unroll
                for (int k = 15; k >= 0; --k) {
                    float yk = R[k >> 2][16] * __builtin_amdgcn_rcpf(R[k >> 2][k]);
                    yk = __shfl(yk, (l & ~3) | (k & 3));
                    ys[k >> 2] = (lam == (k & 3)) ? yk : ys[k >> 2];
                    #pragma unroll
                    for (int i = 0; i < 4; ++i) {
                        int gr = lam + 4*i;
                        float m = (gr < k) ? yk : 0.0f;
                        R[i][16] -= R[i][k] * m;
                    }
                }
                #pragma unroll
                for (int i = 0; i < 4; ++i) sKV[pl*SW_P + lam + 4*i] = ys[i];
            }
            F();
            // ======== RK4 combine (lane: p=pl, vals 8c4..8c4+7) ========
            {
                f32x4 zc0 = *(const f32x4*)&sZC[pl*SZ_P + 8*c4];
                f32x4 zc1 = *(const f32x4*)&sZC[pl*SZ_P + 8*c4 + 4];
                const float* kp = (c4 < 2) ? &sZI[pl*SZ_P + 16 + 8*c4] : &sKV[pl*SW_P + 8*(c4 - 2)];
                f32x4 k0 = *(const f32x4*)&kp[0];
                f32x4 k1 = *(const f32x4*)&kp[4];
                f32x4 a0, a1;
                if (s == 0) { a0 = k0; a1 = k1; }
                else {
                    a0 = *(const f32x4*)&sAC[pl*SZ_P + 8*c4];
                    a1 = *(const f32x4*)&sAC[pl*SZ_P + 8*c4 + 4];
                    float wgt = (s == 3) ? 1.0f : 2.0f;
                    #pragma unroll
                    for (int j = 0; j < 4; ++j) { a0[j] += wgt * k0[j]; a1[j] += wgt * k1[j]; }
                }
                if (s < 3) {
                    *(f32x4*)&sAC[pl*SZ_P + 8*c4]     = a0;
                    *(f32x4*)&sAC[pl*SZ_P + 8*c4 + 4] = a1;
                    float alpha = (s < 2) ? (0.5f * dt) : dt;
                    f32x4 zi0, zi1;
                    #pragma unroll
                    for (int j = 0; j < 4; ++j) { zi0[j] = zc0[j] + alpha * k0[j]; zi1[j] = zc1[j] + alpha * k1[j]; }
                    *(f32x4*)&sZI[pl*SZ_P + 8*c4]     = zi0;
                    *(f32x4*)&sZI[pl*SZ_P + 8*c4 + 4] = zi1;
                } else {
                    float c6 = dt / 6.0f;
                    #pragma unroll
                    for (int j = 0; j < 4; ++j) { zc0[j] += c6 * a0[j]; zc1[j] += c6 * a1[j]; }
                    *(f32x4*)&sZC[pl*SZ_P + 8*c4]     = zc0;
                    *(f32x4*)&sZC[pl*SZ_P + 8*c4 + 4] = zc1;
                }
            }
            F();
        }
    }
    // ---------------- store ----------------
    if (pb + pl < B) {
        f32x4 a = *(const f32x4*)&sZC[pl*SZ_P + 8*c4];
        f32x4 b = *(const f32x4*)&sZC[pl*SZ_P + 8*c4 + 4];
        *(f32x4*)&outg[(pb + pl)*32 + 8*c4]     = a;
        *(f32x4*)&outg[(pb + pl)*32 + 8*c4 + 4] = b;
    }
}

extern "C" void kernel_launch(void* const* d_in, const int* in_sizes, int n_in,
                              void* d_out, int out_size, void* d_ws, size_t ws_size,
                              hipStream_t stream) {
    (void)n_in; (void)d_ws; (void)ws_size; (void)out_size;
    const float* z  = (const float*)d_in[0];
    const float* t  = (const float*)d_in[1];
    const float* W1 = (const float*)d_in[2];
    const float* b1 = (const float*)d_in[3];
    const float* W2 = (const float*)d_in[4];
    const float* b2 = (const float*)d_in[5];
    const int*   ns = (const int*)d_in[6];
    float* out = (float*)d_out;
    const int B = in_sizes[0] / 32;
    int grid = (B + 15) / 16;
    hipLaunchKernelGGL(geo_kernel, dim3(grid), dim3(64), 0, stream,
                       z, t, W1, b1, W2, b2, ns, out, B);
}

// Round 4
// 327.285 us; speedup vs baseline: 4.1105x; 1.0099x over previous
//
#include <hip/hip_runtime.h>
#include <math.h>

// v4: 16 points per BLOCK, 2 cooperating waves (128 thr) splitting every tile
// loop -> each wave hoists only half of each W2 fragment layout (64+64 VGPRs),
// eliminating v3's register spills (v3: 256-VGPR cap + ~380 demand -> 20 MB
// scratch traffic). 1024 blocks -> 8 waves/CU = 2/SIMD.
// dv = G^{-1} aug,  G = A A^T + I,  aug = sum_n W1[i][n] (h_n^2-1) r_n
// (signs/factors folded; same verified math as v3).

typedef _Float16 f16;
typedef _Float16 f16x4 __attribute__((ext_vector_type(4)));
typedef _Float16 f16x8 __attribute__((ext_vector_type(8)));
typedef float f32x4 __attribute__((ext_vector_type(4)));
typedef float f32x16 __attribute__((ext_vector_type(16)));

#define SAG_P 392   // f16 point stride (row stride 24; 196 dw % 32 = 4 -> conflict-safe)
#define SZ_P 36     // f32
#define SH_P 72     // f16
#define SW_P 20     // f32

__device__ __forceinline__ float fastTanh(float x) {
    float e = exp2f(x * 2.885390081777927f);
    return 1.0f - 2.0f * __builtin_amdgcn_rcpf(1.0f + e);
}

__global__ __launch_bounds__(128, 2)
void geo_kernel(const float* __restrict__ zin, const float* __restrict__ tg,
                const float* __restrict__ W1g, const float* __restrict__ b1g,
                const float* __restrict__ W2g, const float* __restrict__ b2g,
                const int* __restrict__ nsg, float* __restrict__ outg, int B)
{
    __shared__ __align__(16) f16   sAG[16 * SAG_P];  // A, then G (aug col at 16)
    __shared__ __align__(16) f16   sHT[16 * SH_P];   // h, then t
    __shared__ __align__(16) float sZI[16 * SZ_P];
    __shared__ __align__(16) float sWw[16 * SW_P];
    __shared__ __align__(16) float sKV[16 * SW_P];

    const int tid = threadIdx.x;
    const int w = tid >> 6;               // wave id 0/1
    const int l = tid & 63;
    const int i16 = l & 15, q4 = l >> 4, h2 = l >> 5, sc = q4 & 1;

    // ---------------- hoisted weights (HALF per wave) ----------------
    f16x8 w2a[8][2];   // A-stage B-frag, tiles t = 8w+t' : W2[n=8q4+j+32ch][e=i16+16t]
    #pragma unroll
    for (int t = 0; t < 8; ++t)
        #pragma unroll
        for (int ch = 0; ch < 2; ++ch)
            #pragma unroll
            for (int j = 0; j < 8; ++j)
                w2a[t][ch][j] = (f16)W2g[(8*q4 + j + 32*ch)*256 + i16 + 16*(8*w + t)];

    f16x8 w2r[2][8];   // r-stage B-frag, tiles t = 2w+t' : W2[n=i16+16t][e=8q4+j+32ch]
    #pragma unroll
    for (int t = 0; t < 2; ++t)
        #pragma unroll
        for (int ch = 0; ch < 8; ++ch)
            #pragma unroll
            for (int j = 0; j < 8; ++j)
                w2r[t][ch][j] = (f16)W2g[(i16 + 16*(2*w + t))*256 + 8*q4 + j + 32*ch];

    f16x8 w1h[2];      // H-stage B-frag (K zero-padded 16->32), tiles t = 2w+t'
    #pragma unroll
    for (int t = 0; t < 2; ++t)
        #pragma unroll
        for (int j = 0; j < 8; ++j) {
            int k = 8*q4 + j;
            w1h[t][j] = (k < 16) ? (f16)W1g[k*64 + i16 + 16*(2*w + t)] : (f16)0.0f;
        }

    f16x8 w1q[2];      // q-stage B-frag (wave 0 only): W1[i=i16][n=8q4+j+32ch]
    if (w == 0) {
        #pragma unroll
        for (int ch = 0; ch < 2; ++ch)
            #pragma unroll
            for (int j = 0; j < 8; ++j)
                w1q[ch][j] = (f16)W1g[i16*64 + 8*q4 + j + 32*ch];
    }

    float b2v[8], b1v[2];
    #pragma unroll
    for (int t = 0; t < 8; ++t) b2v[t] = b2g[i16 + 16*(8*w + t)];
    #pragma unroll
    for (int t = 0; t < 2; ++t) b1v[t] = b1g[i16 + 16*(2*w + t)];

    // ---------------- RK4 state in combine-lane registers ----------------
    const int pb = blockIdx.x * 16;
    const int p_cmb = 8*w + (l >> 3);     // combine/solve point ownership per wave
    const int g8 = l & 7;                 // 4-value group within z (32 vals)
    f32x4 zc, ar;
    {
        int pg = (pb + p_cmb < B) ? (pb + p_cmb) : (B - 1);
        zc = *(const f32x4*)&zin[pg*32 + 4*g8];
        *(f32x4*)&sZI[p_cmb*SZ_P + 4*g8] = zc;
    }
    __syncthreads();

    const float tv = tg[0];
    const int nst = nsg[0];
    const float dt = tv / (float)nst;

    float dreg[2][4];                     // (h^2-1) for this wave's t-tiles

    #pragma unroll 1
    for (int st = 0; st < nst; ++st) {
        #pragma unroll 1
        for (int s = 0; s < 4; ++s) {
            // ---- per-eval x,v loads (lane p = i16) ----
            float vreg[16];
            f16x8 xf;
            {
                f32x4 xa = *(const f32x4*)&sZI[i16*SZ_P + 8*sc];
                f32x4 xb = *(const f32x4*)&sZI[i16*SZ_P + 8*sc + 4];
                #pragma unroll
                for (int j = 0; j < 4; ++j) { xf[j] = (f16)xa[j]; xf[4+j] = (f16)xb[j]; }
                #pragma unroll
                for (int m = 0; m < 4; ++m) {
                    f32x4 v4 = *(const f32x4*)&sZI[i16*SZ_P + 16 + 4*m];
                    #pragma unroll
                    for (int j = 0; j < 4; ++j) vreg[4*m + j] = v4[j];
                }
            }
            // ======== H-stage (split: 2 tiles per wave) ========
            #pragma unroll
            for (int t = 0; t < 2; ++t) {
                f32x4 hc = {0.f, 0.f, 0.f, 0.f};
                hc = __builtin_amdgcn_mfma_f32_16x16x32_f16(xf, w1h[t], hc, 0, 0, 0);
                #pragma unroll
                for (int reg = 0; reg < 4; ++reg) {
                    float hv = fastTanh(hc[reg] + b1v[t]);
                    dreg[t][reg] = hv*hv - 1.0f;
                    sHT[(4*q4 + reg)*SH_P + i16 + 16*(2*w + t)] = (f16)hv;
                }
            }
            __syncthreads();   // B1: h ready
            // ======== A-stage (split: 8 e-tiles per wave) ========
            {
                f16x8 hf0 = *(const f16x8*)&sHT[i16*SH_P + 8*q4];
                f16x8 hf1 = *(const f16x8*)&sHT[i16*SH_P + 8*q4 + 32];
                #pragma unroll
                for (int t = 0; t < 8; ++t) {
                    f32x4 ac = {0.f, 0.f, 0.f, 0.f};
                    ac = __builtin_amdgcn_mfma_f32_16x16x32_f16(hf0, w2a[t][0], ac, 0, 0, 0);
                    ac = __builtin_amdgcn_mfma_f32_16x16x32_f16(hf1, w2a[t][1], ac, 0, 0, 0);
                    #pragma unroll
                    for (int reg = 0; reg < 4; ++reg)
                        sAG[(4*q4 + reg)*SAG_P + 24*(8*w + t) + i16] = (f16)(ac[reg] + b2v[t]);
                }
            }
            __syncthreads();   // B2: A ready
            // ======== w-stage (redundant on both waves): w_c = sum_a v_a A[a][c] ========
            {
                float w4[4] = {0.f, 0.f, 0.f, 0.f};
                #pragma unroll
                for (int a = 0; a < 16; ++a) {
                    f16x4 av = *(const f16x4*)&sAG[i16*SAG_P + 24*a + 4*q4];
                    #pragma unroll
                    for (int u = 0; u < 4; ++u) w4[u] += vreg[a] * (float)av[u];
                }
                f32x4 wv4 = {w4[0], w4[1], w4[2], w4[3]};
                *(f32x4*)&sWw[i16*SW_P + 4*q4] = wv4;
            }
            __syncthreads();   // B3: w ready; all A reads done (G may overwrite)
            // ======== AAT (split: 4 pairs per wave) -> G over A region ========
            #pragma unroll
            for (int u0 = 0; u0 < 4; ++u0) {
                int u = 4*w + u0;
                f16x8 af = *(const f16x8*)&sAG[(2*u + sc)*SAG_P + 24*i16 + 8*h2];
                f32x16 gz = {0.f};
                f32x16 gacc = __builtin_amdgcn_mfma_f32_32x32x16_f16(af, af, gz, 0, 0, 0);
                #pragma unroll
                for (int rr = 0; rr < 8; ++rr) {
                    int a_ = (rr & 3) + 8*(rr >> 2) + 4*h2;
                    float gv = gacc[rr + 8*sc] + ((a_ == i16) ? 1.0f : 0.0f);
                    sAG[(2*u + sc)*SAG_P + 24*a_ + i16] = (f16)gv;
                }
            }
            // ======== r-stage (split: 2 n-tiles per wave): R = (v (x) w) @ W2^T ========
            {
                f32x4 racc[2];
                #pragma unroll
                for (int t = 0; t < 2; ++t) { f32x4 z = {0.f,0.f,0.f,0.f}; racc[t] = z; }
                float wv[8];
                {
                    f32x4 wa = *(const f32x4*)&sWw[i16*SW_P + 8*sc];
                    f32x4 wb = *(const f32x4*)&sWw[i16*SW_P + 8*sc + 4];
                    #pragma unroll
                    for (int j = 0; j < 4; ++j) { wv[j] = wa[j]; wv[4+j] = wb[j]; }
                }
                #pragma unroll
                for (int ch = 0; ch < 8; ++ch) {
                    float vv = vreg[2*ch + (q4 >> 1)];
                    f16x8 uf;
                    #pragma unroll
                    for (int j = 0; j < 8; ++j) uf[j] = (f16)(vv * wv[j]);
                    #pragma unroll
                    for (int t = 0; t < 2; ++t)
                        racc[t] = __builtin_amdgcn_mfma_f32_16x16x32_f16(uf, w2r[t][ch], racc[t], 0, 0, 0);
                }
                // r-epilogue: T = (h^2-1) * R  (d is lane-local: same (p,n) map as H-epi)
                #pragma unroll
                for (int t = 0; t < 2; ++t)
                    #pragma unroll
                    for (int reg = 0; reg < 4; ++reg)
                        sHT[(4*q4 + reg)*SH_P + i16 + 16*(2*w + t)] =
                            (f16)(dreg[t][reg] * racc[t][reg]);
            }
            __syncthreads();   // B4: t ready, G ready
            // ======== q-stage (wave 0): aug = T @ W1^T -> sAG[p][i][16] ========
            if (w == 0) {
                f16x8 tf0 = *(const f16x8*)&sHT[i16*SH_P + 8*q4];
                f16x8 tf1 = *(const f16x8*)&sHT[i16*SH_P + 8*q4 + 32];
                f32x4 qa = {0.f, 0.f, 0.f, 0.f};
                qa = __builtin_amdgcn_mfma_f32_16x16x32_f16(tf0, w1q[0], qa, 0, 0, 0);
                qa = __builtin_amdgcn_mfma_f32_16x16x32_f16(tf1, w1q[1], qa, 0, 0, 0);
                #pragma unroll
                for (int reg = 0; reg < 4; ++reg)
                    sAG[(4*q4 + reg)*SAG_P + 24*i16 + 16] = (f16)qa[reg];
            }
            __syncthreads();   // B5: aug ready
            // ======== solve G y = aug (wave w owns points 8w..8w+7; halves duplicate) ========
            {
                const int psl = 8*w + ((l >> 2) & 7);
                const int lam = l & 3;
                float R[4][17];
                #pragma unroll
                for (int i = 0; i < 4; ++i) {
                    const f16* rp = &sAG[psl*SAG_P + 24*(lam + 4*i)];
                    f16x8 ra = *(const f16x8*)&rp[0];
                    f16x8 rb = *(const f16x8*)&rp[8];
                    #pragma unroll
                    for (int j = 0; j < 8; ++j) { R[i][j] = (float)ra[j]; R[i][8+j] = (float)rb[j]; }
                    R[i][16] = (float)rp[16];
                }
                #pragma unroll
                for (int k = 0; k < 16; ++k) {
                    const int src = (l & ~3) | (k & 3);
                    float pv[17];
                    #pragma unroll
                    for (int j = k; j < 17; ++j) pv[j] = __shfl(R[k >> 2][j], src);
                    float pinv = __builtin_amdgcn_rcpf(pv[k]);
                    #pragma unroll
                    for (int i = 0; i < 4; ++i) {
                        int gr = lam + 4*i;
                        float f = (gr > k) ? (R[i][k] * pinv) : 0.0f;
                        #pragma unroll
                        for (int j = k + 1; j < 17; ++j) R[i][j] -= f * pv[j];
                    }
                }
                float ys[4];
                #pragma unroll
                for (int i = 0; i < 4; ++i) ys[i] = 0.0f;
                #pragma unroll
                for (int k = 15; k >= 0; --k) {
                    float yk = R[k >> 2][16] * __builtin_amdgcn_rcpf(R[k >> 2][k]);
                    yk = __shfl(yk, (l & ~3) | (k & 3));
                    ys[k >> 2] = (lam == (k & 3)) ? yk : ys[k >> 2];
                    #pragma unroll
                    for (int i = 0; i < 4; ++i) {
                        int gr = lam + 4*i;
                        float m = (gr < k) ? yk : 0.0f;
                        R[i][16] -= R[i][k] * m;
                    }
                }
                #pragma unroll
                for (int i = 0; i < 4; ++i) sKV[psl*SW_P + lam + 4*i] = ys[i];
            }
            // (no barrier: solve and combine share point ownership per wave; DS in-order)
            // ======== RK4 combine (lane: p=p_cmb, vals 4g8..4g8+3) ========
            {
                f32x4 kk;
                if (g8 < 4) kk = *(const f32x4*)&sZI[p_cmb*SZ_P + 16 + 4*g8];
                else        kk = *(const f32x4*)&sKV[p_cmb*SW_P + 4*(g8 - 4)];
                if (s == 0) ar = kk;
                else {
                    float wgt = (s == 3) ? 1.0f : 2.0f;
                    #pragma unroll
                    for (int j = 0; j < 4; ++j) ar[j] += wgt * kk[j];
                }
                f32x4 zi;
                if (s < 3) {
                    float alpha = (s < 2) ? (0.5f * dt) : dt;
                    #pragma unroll
                    for (int j = 0; j < 4; ++j) zi[j] = zc[j] + alpha * kk[j];
                } else {
                    float c6 = dt / 6.0f;
                    #pragma unroll
                    for (int j = 0; j < 4; ++j) zc[j] += c6 * ar[j];
                    zi = zc;   // next step's s=0 evaluates at zC
                }
                *(f32x4*)&sZI[p_cmb*SZ_P + 4*g8] = zi;
            }
            __syncthreads();   // B6: zI ready for next eval
        }
    }
    if (pb + p_cmb < B)
        *(f32x4*)&outg[(pb + p_cmb)*32 + 4*g8] = zc;
}

extern "C" void kernel_launch(void* const* d_in, const int* in_sizes, int n_in,
                              void* d_out, int out_size, void* d_ws, size_t ws_size,
                              hipStream_t stream) {
    (void)n_in; (void)d_ws; (void)ws_size; (void)out_size;
    const float* z  = (const float*)d_in[0];
    const float* t  = (const float*)d_in[1];
    const float* W1 = (const float*)d_in[2];
    const float* b1 = (const float*)d_in[3];
    const float* W2 = (const float*)d_in[4];
    const float* b2 = (const float*)d_in[5];
    const int*   ns = (const int*)d_in[6];
    float* out = (float*)d_out;
    const int B = in_sizes[0] / 32;
    int grid = (B + 15) / 16;
    hipLaunchKernelGGL(geo_kernel, dim3(grid), dim3(128), 0, stream,
                       z, t, W1, b1, W2, b2, ns, out, B);
}